// Round 4
// baseline (656.880 us; speedup 1.0000x reference)
//
#include <hip/hip_runtime.h>
#include <hip/hip_bf16.h>
#include <math.h>

#define B_ 16
#define L_ 32768
#define H_ 64
#define N_ 16
#define DM_ 32
#define TS_ 16   /* subtile rows (tied to MFMA M=16) */
#define US_ 68   /* uld row stride: 4*US_ ≡ 16 (mod 32) -> 2-way (free) write banks */

typedef __attribute__((ext_vector_type(8))) short short8;
typedef __attribute__((ext_vector_type(4))) float floatx4;
typedef __attribute__((ext_vector_type(2))) float f32x2;

// gelu matching jax.nn.gelu(approximate=True)
__device__ __forceinline__ float fast_gelu(float v) {
    float z = fmaf(0.044715f * v, v * v, v) * 0.7978845608028654f;
#if __has_builtin(__builtin_amdgcn_exp2f) && __has_builtin(__builtin_amdgcn_rcpf)
    float e = __builtin_amdgcn_exp2f(z * 2.8853900817779268f);
    float t = 1.0f - 2.0f * __builtin_amdgcn_rcpf(e + 1.0f);
#else
    float t = tanhf(z);
#endif
    return 0.5f * v * (1.0f + t);
}

__device__ __forceinline__ unsigned short bf16_rne(float f) {
    unsigned u = __float_as_uint(f);
    return (unsigned short)((u + 0x7FFFu + ((u >> 16) & 1u)) >> 16);
}
__device__ __forceinline__ float bf16_tof(unsigned short h) {
    return __uint_as_float(((unsigned)h) << 16);
}
// split 8 floats into bf16 hi + bf16 lo fragments (packed)
__device__ __forceinline__ void cvt8(const float* f, short8* hi, short8* lo) {
    union { unsigned u[4]; short8 s; } Hh, Ll;
    #pragma unroll
    for (int jp = 0; jp < 4; ++jp) {
        unsigned short h0 = bf16_rne(f[2*jp]), h1 = bf16_rne(f[2*jp+1]);
        Hh.u[jp] = (unsigned)h0 | ((unsigned)h1 << 16);
        float l0 = f[2*jp]   - bf16_tof(h0);
        float l1 = f[2*jp+1] - bf16_tof(h1);
        Ll.u[jp] = (unsigned)bf16_rne(l0) | ((unsigned)bf16_rne(l1) << 16);
    }
    *hi = Hh.s; *lo = Ll.s;
}

// ---- packed complex scan step: s = w*s + (uv, 0) with w=(wr,wi), s=(sr,si) ----
// Bit-exact with: nr=fmaf(wr,sr,fmaf(-wi,si,uv)); ni=fmaf(wr,si,wi*sr)
__device__ __forceinline__ void pk_step(f32x2& s, f32x2 w, f32x2 uv0) {
    f32x2 t;
    asm("v_pk_fma_f32 %0, %1, %2, %3 op_sel:[1,1,0] op_sel_hi:[1,0,1] neg_lo:[1,0,0]"
        : "=v"(t) : "v"(w), "v"(s), "v"(uv0));
    asm("v_pk_fma_f32 %0, %1, %0, %2 op_sel_hi:[0,1,1]"
        : "+v"(s) : "v"(w), "v"(t));
}
// y += (c.lo*s.lo, c.hi*s.hi)
__device__ __forceinline__ void pk_acc(f32x2& y, f32x2 c, f32x2 s) {
    asm("v_pk_fma_f32 %0, %1, %2, %0"
        : "+v"(y) : "v"(c), "v"(s));
}

// ---------------- kernel 0a: cond MLP + FiLM params ----------------
__global__ void cond_film_kernel(const float* __restrict__ cp,
    const float* __restrict__ W0, const float* __restrict__ b0,
    const float* __restrict__ W1, const float* __restrict__ b1,
    const float* __restrict__ W2, const float* __restrict__ b2,
    const float* __restrict__ Wf, const float* __restrict__ bf,
    float* __restrict__ film) {
    __shared__ float ca[B_][DM_];
    __shared__ float cb[B_][DM_];
    int tid = threadIdx.x;            // 512 threads = 16 b * 32 j
    int b = tid >> 5, j = tid & 31;
    float acc = fmaf(cp[b*2+0], W0[j], fmaf(cp[b*2+1], W0[DM_+j], b0[j]));
    ca[b][j] = fast_gelu(acc);
    __syncthreads();
    acc = b1[j];
    #pragma unroll
    for (int i = 0; i < DM_; ++i) acc = fmaf(ca[b][i], W1[i*DM_+j], acc);
    cb[b][j] = fast_gelu(acc);
    __syncthreads();
    acc = b2[j];
    #pragma unroll
    for (int i = 0; i < DM_; ++i) acc = fmaf(cb[b][i], W2[i*DM_+j], acc);
    float c2 = fast_gelu(acc);
    __syncthreads();
    ca[b][j] = c2;
    __syncthreads();
    #pragma unroll
    for (int t = 0; t < 4; ++t) {
        int k = j + DM_*t;            // 0..127
        float a = bf[k];
        #pragma unroll
        for (int i = 0; i < DM_; ++i) a = fmaf(ca[b][i], Wf[i*2*H_+k], a);
        film[b*2*H_ + k] = a;         // [0:64)=gamma, [64:128)=beta
    }
}

// ---------------- kernel 0b: SSM coefficients ----------------
// coef layout: coef[(n*6+f)*H_ + h], f = {wr, wi, wTr, wTi, 2cr, 2ci}
// Tf = chunk length (runtime so T-split can adapt to workspace size)
__global__ void coef_kernel(const float* __restrict__ log_dt,
    const float* __restrict__ A_re, const float* __restrict__ A_im,
    const float* __restrict__ C_re, const float* __restrict__ C_im,
    float* __restrict__ coef, float Tf) {
    int g = blockIdx.x * blockDim.x + threadIdx.x;   // 1024
    if (g >= H_*N_) return;
    int h = g >> 4, n = g & 15;
    float dt = expf(log_dt[h]);
    float Ar = A_re[h*N_+n], Ai = A_im[h*N_+n];
    float ar = dt*Ar, ai = dt*Ai;
    float er = expf(ar);
    float wr = er * cosf(ai), wi = er * sinf(ai);
    float eT = expf(Tf * ar);
    float aT = Tf * ai;
    float wTr = eT * cosf(aT), wTi = eT * sinf(aT);
    float d  = Ar*Ar + Ai*Ai;
    float nr = wr - 1.0f, ni = wi;
    float qr = (nr*Ar + ni*Ai) / d;
    float qi = (ni*Ar - nr*Ai) / d;
    float Cr = C_re[h*N_+n], Ci = C_im[h*N_+n];
    float cr = 2.0f * (Cr*qr - Ci*qi);   // fold the 2*Re() factor in
    float ci = 2.0f * (Cr*qi + Ci*qr);
    coef[(n*6+0)*H_+h] = wr;
    coef[(n*6+1)*H_+h] = wi;
    coef[(n*6+2)*H_+h] = wTr;
    coef[(n*6+3)*H_+h] = wTi;
    coef[(n*6+4)*H_+h] = cr;
    coef[(n*6+5)*H_+h] = ci;
}

// ---------------- phase 2: cross-chunk prefix combine (prefetch depth 8) ----
// states layout: states[(((b*Cc + c)*N_ + n)*H_ + h)*2 + {0,1}]
__global__ void chunk_scan_kernel(float* __restrict__ states,
                                  const float* __restrict__ coef, int Cc) {
    int t = blockIdx.x * blockDim.x + threadIdx.x;   // 16384 = B*N*H
    int h = t & 63, n = (t >> 6) & 15, b = t >> 10;
    float wTr = coef[(n*6+2)*H_+h], wTi = coef[(n*6+3)*H_+h];
    float2* sp = (float2*)states + ((size_t)b*Cc)*N_*H_ + (size_t)n*H_ + h;
    const int stride = N_*H_;        // float2 units per chunk
    float car = 0.f, cai = 0.f;
    float2 buf[8];
    #pragma unroll
    for (int i = 0; i < 8; ++i) buf[i] = sp[(size_t)i*stride];
    for (int cg = 0; cg < Cc; cg += 8) {
        float2 nb[8];
        #pragma unroll
        for (int i = 0; i < 8; ++i)
            nb[i] = (cg + 8 + i < Cc) ? sp[(size_t)(cg+8+i)*stride]
                                      : make_float2(0.f, 0.f);
        #pragma unroll
        for (int i = 0; i < 8; ++i) {
            float2 v = buf[i];
            sp[(size_t)(cg+i)*stride] = make_float2(car, cai);
            float nr2 = fmaf(wTr, car, fmaf(-wTi, cai, v.x));
            float ni2 = fmaf(wTr, cai, fmaf( wTi, car, v.y));
            car = nr2; cai = ni2;
            buf[i] = nb[i];
        }
    }
}

// ---------------- phases 1 & 3: MFMA GEMM + diagonal scan ----------------
// PHASE 1: zero-init states, write end-of-chunk local states.
// PHASE 3: init from prefix states, write final output (FiLM+gelu+gate fused).
// CC = chunks per batch (L_/CC = chunk length). One wave per chunk, 4 waves/block.
// u = gelu(x@W+b) via split-bf16 MFMA; scan on packed fp32 (v_pk_fma_f32).
// Latency plan: A-fragments double-buffered across subtiles; gate x values
// prefetched into regs at subtile top (L1/L2 hits, consumed ~1-2k cy later);
// scan l-loop fully unrolled (static xg[] indexing, hoistable ds_reads).
// LDS = 33.8 KB -> 4 blocks/CU; __launch_bounds__(256,4) caps VGPR at 128.
template<int PHASE, int CC>
__global__ __launch_bounds__(256, 4)
void gemm_scan_kernel(const float* __restrict__ x,
                      const float* __restrict__ W_lin, const float* __restrict__ b_lin,
                      const float* __restrict__ coef, float* __restrict__ states,
                      const float* __restrict__ D, const float* __restrict__ film,
                      float* __restrict__ out) {
    constexpr int TT = L_/CC;                 // chunk length
    constexpr int NS = TT/TS_;                // subtiles per chunk
    // W fragment table: frag f = (t*2+kt)*4+nt (t=0 hi, t=1 lo), 16 frags * 64 lanes * 16B
    __shared__ __align__(16) unsigned short Wf[16*64*8];     // 16 KB
    __shared__ float uld[4][TS_*US_];                         // 4 * 4.25 KB
    const int lane = threadIdx.x & 63;
    const int wv   = threadIdx.x >> 6;
    const int q    = blockIdx.x*4 + wv;        // chunk id 0..B_*CC-1
    const int b    = q / CC;
    const int c    = q % CC;
    const int m    = lane & 15;
    const int quad = lane >> 4;

    // ---- build W fragments in LDS (each wave writes full table; identical values,
    //      so no barrier needed — per-wave DS ordering covers own writes) ----
    for (int kt = 0; kt < 2; ++kt)
        for (int nt = 0; nt < 4; ++nt) {
            float f[8];
            #pragma unroll
            for (int j = 0; j < 8; ++j)
                f[j] = W_lin[(kt*32 + quad*8 + j)*H_ + nt*16 + m];
            short8 hi, lo;
            cvt8(f, &hi, &lo);
            ((short8*)Wf)[(kt*4 + nt)*64 + lane]     = hi;   // t=0
            ((short8*)Wf)[((2+kt)*4 + nt)*64 + lane] = lo;   // t=1
        }

    // ---- scan coefficients / state init (packed pairs) ----
    f32x2 w2[N_], s2[N_], c2[N_];
    float g_ = 0.f, be_ = 0.f, Dh = 0.f;
    #pragma unroll
    for (int n = 0; n < N_; ++n) {
        w2[n].x = coef[(n*6+0)*H_ + lane];
        w2[n].y = coef[(n*6+1)*H_ + lane];
    }
    if (PHASE == 1) {
        #pragma unroll
        for (int n = 0; n < N_; ++n) s2[n] = (f32x2){0.f, 0.f};
    } else {
        #pragma unroll
        for (int n = 0; n < N_; ++n) {
            c2[n].x = coef[(n*6+4)*H_ + lane];
            c2[n].y = coef[(n*6+5)*H_ + lane];
            size_t idx = (((size_t)q*N_ + n)*H_ + lane)*2;
            s2[n] = *(const f32x2*)(states + idx);
        }
        g_  = film[b*2*H_ + lane];
        be_ = film[b*2*H_ + H_ + lane];
        Dh  = D[lane];
    }
    float blv[4];
    #pragma unroll
    for (int nt = 0; nt < 4; ++nt) blv[nt] = b_lin[nt*16 + m];

    const float* xp = x + ((size_t)b*L_ + (size_t)c*TT)*H_;
    float* op = out + ((size_t)b*L_ + (size_t)c*TT)*H_;
    float* myu = uld[wv];

    // A-fragment prologue load for s=0: A[m][k=kt*32+quad*8+j]
    float4 a0[2], a1[2];
    #pragma unroll
    for (int kt = 0; kt < 2; ++kt) {
        const float* src = xp + m*H_ + kt*32 + quad*8;
        a0[kt] = *(const float4*)(src);
        a1[kt] = *(const float4*)(src + 4);
    }

    for (int s = 0; s < NS; ++s) {
        const float* xs = xp + s*TS_*H_;
        // gate prefetch into regs (phase 3): row l, col lane — L1/L2 hits
        float xg[TS_];
        if (PHASE == 3) {
            #pragma unroll
            for (int l = 0; l < TS_; ++l) xg[l] = xs[l*H_ + lane];
        }
        // next-subtile A prefetch (hides HBM latency under MFMA+scan)
        float4 n0[2], n1[2];
        if (s + 1 < NS) {
            #pragma unroll
            for (int kt = 0; kt < 2; ++kt) {
                const float* src = xs + TS_*H_ + m*H_ + kt*32 + quad*8;
                n0[kt] = *(const float4*)(src);
                n1[kt] = *(const float4*)(src + 4);
            }
        }
        // convert current A regs to split-bf16 fragments
        short8 ah[2], al[2];
        #pragma unroll
        for (int kt = 0; kt < 2; ++kt) {
            float f[8] = {a0[kt].x, a0[kt].y, a0[kt].z, a0[kt].w,
                          a1[kt].x, a1[kt].y, a1[kt].z, a1[kt].w};
            cvt8(f, &ah[kt], &al[kt]);
        }
        // MFMA + epilogue: gelu, transpose u through LDS (row stride US_)
        #pragma unroll
        for (int nt = 0; nt < 4; ++nt) {
            floatx4 acc = {0.f, 0.f, 0.f, 0.f};
            #pragma unroll
            for (int kt = 0; kt < 2; ++kt) {
                short8 bh = ((short8*)Wf)[(kt*4 + nt)*64 + lane];
                short8 bl = ((short8*)Wf)[((2+kt)*4 + nt)*64 + lane];
                acc = __builtin_amdgcn_mfma_f32_16x16x32_bf16(ah[kt], bh, acc, 0, 0, 0);
                acc = __builtin_amdgcn_mfma_f32_16x16x32_bf16(al[kt], bh, acc, 0, 0, 0);
                acc = __builtin_amdgcn_mfma_f32_16x16x32_bf16(ah[kt], bl, acc, 0, 0, 0);
            }
            // C layout: col = nt*16 + (lane&15), row = quad*4 + reg
            #pragma unroll
            for (int r = 0; r < 4; ++r) {
                int row = quad*4 + r;
                float uv = fast_gelu(acc[r] + blv[nt]);
                myu[row*US_ + nt*16 + m] = uv;
            }
        }
        // scan TS_ rows (lane = h); fully unrolled, xg[] static-indexed
        #pragma unroll
        for (int l = 0; l < TS_; ++l) {
            float uv = myu[l*US_ + lane];
            f32x2 uv0 = {uv, 0.f};
            if (PHASE == 1) {
                #pragma unroll
                for (int n = 0; n < N_; ++n) pk_step(s2[n], w2[n], uv0);
            } else {
                f32x2 y2 = {0.f, 0.f};
                #pragma unroll
                for (int n = 0; n < N_; ++n) {
                    pk_step(s2[n], w2[n], uv0);
                    pk_acc(y2, c2[n], s2[n]);
                }
                float y  = fmaf(Dh, uv, y2.x - y2.y);   // conv + D*u
                float yg = fast_gelu(fmaf(y, g_, be_)); // FiLM + gelu
                op[(s*TS_ + l)*H_ + lane] = xg[l] * yg; // side-chain gate
            }
        }
        // rotate A double-buffer
        #pragma unroll
        for (int kt = 0; kt < 2; ++kt) { a0[kt] = n0[kt]; a1[kt] = n1[kt]; }
    }
    if (PHASE == 1) {
        #pragma unroll
        for (int n = 0; n < N_; ++n) {
            size_t idx = (((size_t)q*N_ + n)*H_ + lane)*2;
            *(f32x2*)(states + idx) = s2[n];
        }
    }
}

extern "C" void kernel_launch(void* const* d_in, const int* in_sizes, int n_in,
                              void* d_out, int out_size, void* d_ws, size_t ws_size,
                              hipStream_t stream) {
    const float* x     = (const float*)d_in[0];
    const float* cp    = (const float*)d_in[1];
    const float* W0    = (const float*)d_in[2];
    const float* b0    = (const float*)d_in[3];
    const float* W1    = (const float*)d_in[4];
    const float* b1    = (const float*)d_in[5];
    const float* W2    = (const float*)d_in[6];
    const float* b2    = (const float*)d_in[7];
    const float* W_lin = (const float*)d_in[8];
    const float* b_lin = (const float*)d_in[9];
    const float* log_dt= (const float*)d_in[10];
    const float* A_re  = (const float*)d_in[11];
    const float* A_im  = (const float*)d_in[12];
    const float* C_re  = (const float*)d_in[13];
    const float* C_im  = (const float*)d_in[14];
    const float* D     = (const float*)d_in[15];
    const float* W_f   = (const float*)d_in[16];
    const float* b_f   = (const float*)d_in[17];
    float* out = (float*)d_out;

    float* film   = (float*)d_ws;                  // B*2H       = 2048 floats
    float* coef   = film + B_*2*H_;                // 6*H*N      = 6144 floats
    float* states = coef + 6*H_*N_;                // B*Cc*N*H*2 floats

    cond_film_kernel<<<1, 512, 0, stream>>>(cp, W0, b0, W1, b1, W2, b2,
                                            W_f, b_f, film);

    // T-split: prefer 64-length chunks (2x parallelism) if workspace allows.
    size_t need64 = (size_t)(B_*2*H_ + 6*H_*N_)*4
                  + (size_t)B_*512*N_*H_*2*4;      // ~64 MiB
    if (ws_size >= need64) {
        coef_kernel<<<4, 256, 0, stream>>>(log_dt, A_re, A_im, C_re, C_im,
                                           coef, 64.0f);
        gemm_scan_kernel<1,512><<<(B_*512)/4, 256, 0, stream>>>(
            x, W_lin, b_lin, coef, states, nullptr, nullptr, nullptr);
        chunk_scan_kernel<<<(B_*N_*H_)/256, 256, 0, stream>>>(states, coef, 512);
        gemm_scan_kernel<3,512><<<(B_*512)/4, 256, 0, stream>>>(
            x, W_lin, b_lin, coef, states, D, film, out);
    } else {
        coef_kernel<<<4, 256, 0, stream>>>(log_dt, A_re, A_im, C_re, C_im,
                                           coef, 128.0f);
        gemm_scan_kernel<1,256><<<(B_*256)/4, 256, 0, stream>>>(
            x, W_lin, b_lin, coef, states, nullptr, nullptr, nullptr);
        chunk_scan_kernel<<<(B_*N_*H_)/256, 256, 0, stream>>>(states, coef, 256);
        gemm_scan_kernel<3,256><<<(B_*256)/4, 256, 0, stream>>>(
            x, W_lin, b_lin, coef, states, D, film, out);
    }
}

// Round 6
// 549.809 us; speedup vs baseline: 1.1947x; 1.1947x over previous
//
#include <hip/hip_runtime.h>
#include <hip/hip_bf16.h>
#include <math.h>

#define B_ 16
#define L_ 32768
#define H_ 64
#define N_ 16
#define DM_ 32
#define TS_ 16   /* subtile rows (tied to MFMA M=16) */
#define US_ 68   /* uld row stride: 4*US_ ≡ 16 (mod 32) -> 2-way (free) write banks */

typedef __attribute__((ext_vector_type(8))) short short8;
typedef __attribute__((ext_vector_type(4))) float floatx4;
typedef __attribute__((ext_vector_type(2))) float f32x2;

// gelu matching jax.nn.gelu(approximate=True)
__device__ __forceinline__ float fast_gelu(float v) {
    float z = fmaf(0.044715f * v, v * v, v) * 0.7978845608028654f;
#if __has_builtin(__builtin_amdgcn_exp2f) && __has_builtin(__builtin_amdgcn_rcpf)
    float e = __builtin_amdgcn_exp2f(z * 2.8853900817779268f);
    float t = 1.0f - 2.0f * __builtin_amdgcn_rcpf(e + 1.0f);
#else
    float t = tanhf(z);
#endif
    return 0.5f * v * (1.0f + t);
}

__device__ __forceinline__ unsigned short bf16_rne(float f) {
    unsigned u = __float_as_uint(f);
    return (unsigned short)((u + 0x7FFFu + ((u >> 16) & 1u)) >> 16);
}
__device__ __forceinline__ float bf16_tof(unsigned short h) {
    return __uint_as_float(((unsigned)h) << 16);
}
// split 8 floats into bf16 hi + bf16 lo fragments (packed)
__device__ __forceinline__ void cvt8(const float* f, short8* hi, short8* lo) {
    union { unsigned u[4]; short8 s; } Hh, Ll;
    #pragma unroll
    for (int jp = 0; jp < 4; ++jp) {
        unsigned short h0 = bf16_rne(f[2*jp]), h1 = bf16_rne(f[2*jp+1]);
        Hh.u[jp] = (unsigned)h0 | ((unsigned)h1 << 16);
        float l0 = f[2*jp]   - bf16_tof(h0);
        float l1 = f[2*jp+1] - bf16_tof(h1);
        Ll.u[jp] = (unsigned)bf16_rne(l0) | ((unsigned)bf16_rne(l1) << 16);
    }
    *hi = Hh.s; *lo = Ll.s;
}

// ---- packed complex scan step: s = w*s + (uv, 0) with w=(wr,wi), s=(sr,si) ----
// Bit-exact with: nr=fmaf(wr,sr,fmaf(-wi,si,uv)); ni=fmaf(wr,si,wi*sr)
__device__ __forceinline__ void pk_step(f32x2& s, f32x2 w, f32x2 uv0) {
    f32x2 t;
    asm("v_pk_fma_f32 %0, %1, %2, %3 op_sel:[1,1,0] op_sel_hi:[1,0,1] neg_lo:[1,0,0]"
        : "=v"(t) : "v"(w), "v"(s), "v"(uv0));
    asm("v_pk_fma_f32 %0, %1, %0, %2 op_sel_hi:[0,1,1]"
        : "+v"(s) : "v"(w), "v"(t));
}
// y += (c.lo*s.lo, c.hi*s.hi)
__device__ __forceinline__ void pk_acc(f32x2& y, f32x2 c, f32x2 s) {
    asm("v_pk_fma_f32 %0, %1, %2, %0"
        : "+v"(y) : "v"(c), "v"(s));
}

// ---------------- kernel 0a: cond MLP + FiLM params ----------------
__global__ void cond_film_kernel(const float* __restrict__ cp,
    const float* __restrict__ W0, const float* __restrict__ b0,
    const float* __restrict__ W1, const float* __restrict__ b1,
    const float* __restrict__ W2, const float* __restrict__ b2,
    const float* __restrict__ Wf, const float* __restrict__ bf,
    float* __restrict__ film) {
    __shared__ float ca[B_][DM_];
    __shared__ float cb[B_][DM_];
    int tid = threadIdx.x;            // 512 threads = 16 b * 32 j
    int b = tid >> 5, j = tid & 31;
    float acc = fmaf(cp[b*2+0], W0[j], fmaf(cp[b*2+1], W0[DM_+j], b0[j]));
    ca[b][j] = fast_gelu(acc);
    __syncthreads();
    acc = b1[j];
    #pragma unroll
    for (int i = 0; i < DM_; ++i) acc = fmaf(ca[b][i], W1[i*DM_+j], acc);
    cb[b][j] = fast_gelu(acc);
    __syncthreads();
    acc = b2[j];
    #pragma unroll
    for (int i = 0; i < DM_; ++i) acc = fmaf(cb[b][i], W2[i*DM_+j], acc);
    float c2 = fast_gelu(acc);
    __syncthreads();
    ca[b][j] = c2;
    __syncthreads();
    #pragma unroll
    for (int t = 0; t < 4; ++t) {
        int k = j + DM_*t;            // 0..127
        float a = bf[k];
        #pragma unroll
        for (int i = 0; i < DM_; ++i) a = fmaf(ca[b][i], Wf[i*2*H_+k], a);
        film[b*2*H_ + k] = a;         // [0:64)=gamma, [64:128)=beta
    }
}

// ---------------- kernel 0b: SSM coefficients ----------------
// coef layout: coef[(n*6+f)*H_ + h], f = {wr, wi, wTr, wTi, 2cr, 2ci}
// Tf = chunk length (runtime so T-split can adapt to workspace size)
__global__ void coef_kernel(const float* __restrict__ log_dt,
    const float* __restrict__ A_re, const float* __restrict__ A_im,
    const float* __restrict__ C_re, const float* __restrict__ C_im,
    float* __restrict__ coef, float Tf) {
    int g = blockIdx.x * blockDim.x + threadIdx.x;   // 1024
    if (g >= H_*N_) return;
    int h = g >> 4, n = g & 15;
    float dt = expf(log_dt[h]);
    float Ar = A_re[h*N_+n], Ai = A_im[h*N_+n];
    float ar = dt*Ar, ai = dt*Ai;
    float er = expf(ar);
    float wr = er * cosf(ai), wi = er * sinf(ai);
    float eT = expf(Tf * ar);
    float aT = Tf * ai;
    float wTr = eT * cosf(aT), wTi = eT * sinf(aT);
    float d  = Ar*Ar + Ai*Ai;
    float nr = wr - 1.0f, ni = wi;
    float qr = (nr*Ar + ni*Ai) / d;
    float qi = (ni*Ar - nr*Ai) / d;
    float Cr = C_re[h*N_+n], Ci = C_im[h*N_+n];
    float cr = 2.0f * (Cr*qr - Ci*qi);   // fold the 2*Re() factor in
    float ci = 2.0f * (Cr*qi + Ci*qr);
    coef[(n*6+0)*H_+h] = wr;
    coef[(n*6+1)*H_+h] = wi;
    coef[(n*6+2)*H_+h] = wTr;
    coef[(n*6+3)*H_+h] = wTi;
    coef[(n*6+4)*H_+h] = cr;
    coef[(n*6+5)*H_+h] = ci;
}

// ---------------- phase 2: cross-chunk prefix combine (prefetch depth 8) ----
// states layout: states[(((b*Cc + c)*N_ + n)*H_ + h)*2 + {0,1}]
__global__ void chunk_scan_kernel(float* __restrict__ states,
                                  const float* __restrict__ coef, int Cc) {
    int t = blockIdx.x * blockDim.x + threadIdx.x;   // 16384 = B*N*H
    int h = t & 63, n = (t >> 6) & 15, b = t >> 10;
    float wTr = coef[(n*6+2)*H_+h], wTi = coef[(n*6+3)*H_+h];
    float2* sp = (float2*)states + ((size_t)b*Cc)*N_*H_ + (size_t)n*H_ + h;
    const int stride = N_*H_;        // float2 units per chunk
    float car = 0.f, cai = 0.f;
    float2 buf[8];
    #pragma unroll
    for (int i = 0; i < 8; ++i) buf[i] = sp[(size_t)i*stride];
    for (int cg = 0; cg < Cc; cg += 8) {
        float2 nb[8];
        #pragma unroll
        for (int i = 0; i < 8; ++i)
            nb[i] = (cg + 8 + i < Cc) ? sp[(size_t)(cg+8+i)*stride]
                                      : make_float2(0.f, 0.f);
        #pragma unroll
        for (int i = 0; i < 8; ++i) {
            float2 v = buf[i];
            sp[(size_t)(cg+i)*stride] = make_float2(car, cai);
            float nr2 = fmaf(wTr, car, fmaf(-wTi, cai, v.x));
            float ni2 = fmaf(wTr, cai, fmaf( wTi, car, v.y));
            car = nr2; cai = ni2;
            buf[i] = nb[i];
        }
    }
}

// ---------------- phases 1 & 3: MFMA GEMM + diagonal scan ----------------
// PHASE 1: zero-init states, write end-of-chunk local states.
// PHASE 3: init from prefix states, write final output (FiLM+gelu+gate fused).
// CC = chunks per batch (L_/CC = chunk length). One wave per chunk, 4 waves/block.
// u = gelu(x@W+b) via split-bf16 MFMA; scan on packed fp32 (v_pk_fma_f32).
// Latency plan: A-fragments double-buffered across subtiles; gate x values
// prefetched into regs at subtile top (L1/L2 hits, consumed ~1-2k cy later);
// scan l-loop fully unrolled (static xg[] indexing, hoistable ds_reads).
// LDS = 33.8 KB (4 blocks/CU feasible).
// NOTE: __launch_bounds__ must stay (256,3): (256,4) caps regs at 128 incl.
// AGPR stash -> ~550 MB scratch spill traffic, dur +46% (measured round 4).
template<int PHASE, int CC>
__global__ __launch_bounds__(256, 3)
void gemm_scan_kernel(const float* __restrict__ x,
                      const float* __restrict__ W_lin, const float* __restrict__ b_lin,
                      const float* __restrict__ coef, float* __restrict__ states,
                      const float* __restrict__ D, const float* __restrict__ film,
                      float* __restrict__ out) {
    constexpr int TT = L_/CC;                 // chunk length
    constexpr int NS = TT/TS_;                // subtiles per chunk
    // W fragment table: frag f = (t*2+kt)*4+nt (t=0 hi, t=1 lo), 16 frags * 64 lanes * 16B
    __shared__ __align__(16) unsigned short Wf[16*64*8];     // 16 KB
    __shared__ float uld[4][TS_*US_];                         // 4 * 4.25 KB
    const int lane = threadIdx.x & 63;
    const int wv   = threadIdx.x >> 6;
    const int q    = blockIdx.x*4 + wv;        // chunk id 0..B_*CC-1
    const int b    = q / CC;
    const int c    = q % CC;
    const int m    = lane & 15;
    const int quad = lane >> 4;

    // ---- build W fragments in LDS (each wave writes full table; identical values,
    //      so no barrier needed — per-wave DS ordering covers own writes) ----
    for (int kt = 0; kt < 2; ++kt)
        for (int nt = 0; nt < 4; ++nt) {
            float f[8];
            #pragma unroll
            for (int j = 0; j < 8; ++j)
                f[j] = W_lin[(kt*32 + quad*8 + j)*H_ + nt*16 + m];
            short8 hi, lo;
            cvt8(f, &hi, &lo);
            ((short8*)Wf)[(kt*4 + nt)*64 + lane]     = hi;   // t=0
            ((short8*)Wf)[((2+kt)*4 + nt)*64 + lane] = lo;   // t=1
        }

    // ---- scan coefficients / state init (packed pairs) ----
    f32x2 w2[N_], s2[N_], c2[N_];
    float g_ = 0.f, be_ = 0.f, Dh = 0.f;
    #pragma unroll
    for (int n = 0; n < N_; ++n) {
        w2[n].x = coef[(n*6+0)*H_ + lane];
        w2[n].y = coef[(n*6+1)*H_ + lane];
    }
    if (PHASE == 1) {
        #pragma unroll
        for (int n = 0; n < N_; ++n) s2[n] = (f32x2){0.f, 0.f};
    } else {
        #pragma unroll
        for (int n = 0; n < N_; ++n) {
            c2[n].x = coef[(n*6+4)*H_ + lane];
            c2[n].y = coef[(n*6+5)*H_ + lane];
            size_t idx = (((size_t)q*N_ + n)*H_ + lane)*2;
            s2[n] = *(const f32x2*)(states + idx);
        }
        g_  = film[b*2*H_ + lane];
        be_ = film[b*2*H_ + H_ + lane];
        Dh  = D[lane];
    }
    float blv[4];
    #pragma unroll
    for (int nt = 0; nt < 4; ++nt) blv[nt] = b_lin[nt*16 + m];

    const float* xp = x + ((size_t)b*L_ + (size_t)c*TT)*H_;
    float* op = out + ((size_t)b*L_ + (size_t)c*TT)*H_;
    float* myu = uld[wv];

    // A-fragment prologue load for s=0: A[m][k=kt*32+quad*8+j]
    float4 a0[2], a1[2];
    #pragma unroll
    for (int kt = 0; kt < 2; ++kt) {
        const float* src = xp + m*H_ + kt*32 + quad*8;
        a0[kt] = *(const float4*)(src);
        a1[kt] = *(const float4*)(src + 4);
    }

    for (int s = 0; s < NS; ++s) {
        const float* xs = xp + s*TS_*H_;
        // gate prefetch into regs (phase 3): row l, col lane — L1/L2 hits
        float xg[TS_];
        if (PHASE == 3) {
            #pragma unroll
            for (int l = 0; l < TS_; ++l) xg[l] = xs[l*H_ + lane];
        }
        // next-subtile A prefetch (hides HBM latency under MFMA+scan)
        float4 n0[2], n1[2];
        if (s + 1 < NS) {
            #pragma unroll
            for (int kt = 0; kt < 2; ++kt) {
                const float* src = xs + TS_*H_ + m*H_ + kt*32 + quad*8;
                n0[kt] = *(const float4*)(src);
                n1[kt] = *(const float4*)(src + 4);
            }
        }
        // convert current A regs to split-bf16 fragments
        short8 ah[2], al[2];
        #pragma unroll
        for (int kt = 0; kt < 2; ++kt) {
            float f[8] = {a0[kt].x, a0[kt].y, a0[kt].z, a0[kt].w,
                          a1[kt].x, a1[kt].y, a1[kt].z, a1[kt].w};
            cvt8(f, &ah[kt], &al[kt]);
        }
        // MFMA + epilogue: gelu, transpose u through LDS (row stride US_)
        #pragma unroll
        for (int nt = 0; nt < 4; ++nt) {
            floatx4 acc = {0.f, 0.f, 0.f, 0.f};
            #pragma unroll
            for (int kt = 0; kt < 2; ++kt) {
                short8 bh = ((short8*)Wf)[(kt*4 + nt)*64 + lane];
                short8 bl = ((short8*)Wf)[((2+kt)*4 + nt)*64 + lane];
                acc = __builtin_amdgcn_mfma_f32_16x16x32_bf16(ah[kt], bh, acc, 0, 0, 0);
                acc = __builtin_amdgcn_mfma_f32_16x16x32_bf16(al[kt], bh, acc, 0, 0, 0);
                acc = __builtin_amdgcn_mfma_f32_16x16x32_bf16(ah[kt], bl, acc, 0, 0, 0);
            }
            // C layout: col = nt*16 + (lane&15), row = quad*4 + reg
            #pragma unroll
            for (int r = 0; r < 4; ++r) {
                int row = quad*4 + r;
                float uv = fast_gelu(acc[r] + blv[nt]);
                myu[row*US_ + nt*16 + m] = uv;
            }
        }
        // scan TS_ rows (lane = h); fully unrolled, xg[] static-indexed
        #pragma unroll
        for (int l = 0; l < TS_; ++l) {
            float uv = myu[l*US_ + lane];
            f32x2 uv0 = {uv, 0.f};
            if (PHASE == 1) {
                #pragma unroll
                for (int n = 0; n < N_; ++n) pk_step(s2[n], w2[n], uv0);
            } else {
                f32x2 y2 = {0.f, 0.f};
                #pragma unroll
                for (int n = 0; n < N_; ++n) {
                    pk_step(s2[n], w2[n], uv0);
                    pk_acc(y2, c2[n], s2[n]);
                }
                float y  = fmaf(Dh, uv, y2.x - y2.y);   // conv + D*u
                float yg = fast_gelu(fmaf(y, g_, be_)); // FiLM + gelu
                op[(s*TS_ + l)*H_ + lane] = xg[l] * yg; // side-chain gate
            }
        }
        // rotate A double-buffer
        #pragma unroll
        for (int kt = 0; kt < 2; ++kt) { a0[kt] = n0[kt]; a1[kt] = n1[kt]; }
    }
    if (PHASE == 1) {
        #pragma unroll
        for (int n = 0; n < N_; ++n) {
            size_t idx = (((size_t)q*N_ + n)*H_ + lane)*2;
            *(f32x2*)(states + idx) = s2[n];
        }
    }
}

extern "C" void kernel_launch(void* const* d_in, const int* in_sizes, int n_in,
                              void* d_out, int out_size, void* d_ws, size_t ws_size,
                              hipStream_t stream) {
    const float* x     = (const float*)d_in[0];
    const float* cp    = (const float*)d_in[1];
    const float* W0    = (const float*)d_in[2];
    const float* b0    = (const float*)d_in[3];
    const float* W1    = (const float*)d_in[4];
    const float* b1    = (const float*)d_in[5];
    const float* W2    = (const float*)d_in[6];
    const float* b2    = (const float*)d_in[7];
    const float* W_lin = (const float*)d_in[8];
    const float* b_lin = (const float*)d_in[9];
    const float* log_dt= (const float*)d_in[10];
    const float* A_re  = (const float*)d_in[11];
    const float* A_im  = (const float*)d_in[12];
    const float* C_re  = (const float*)d_in[13];
    const float* C_im  = (const float*)d_in[14];
    const float* D     = (const float*)d_in[15];
    const float* W_f   = (const float*)d_in[16];
    const float* b_f   = (const float*)d_in[17];
    float* out = (float*)d_out;

    float* film   = (float*)d_ws;                  // B*2H       = 2048 floats
    float* coef   = film + B_*2*H_;                // 6*H*N      = 6144 floats
    float* states = coef + 6*H_*N_;                // B*Cc*N*H*2 floats

    cond_film_kernel<<<1, 512, 0, stream>>>(cp, W0, b0, W1, b1, W2, b2,
                                            W_f, b_f, film);

    // T-split: prefer 64-length chunks (2x parallelism) if workspace allows.
    size_t need64 = (size_t)(B_*2*H_ + 6*H_*N_)*4
                  + (size_t)B_*512*N_*H_*2*4;      // ~64 MiB
    if (ws_size >= need64) {
        coef_kernel<<<4, 256, 0, stream>>>(log_dt, A_re, A_im, C_re, C_im,
                                           coef, 64.0f);
        gemm_scan_kernel<1,512><<<(B_*512)/4, 256, 0, stream>>>(
            x, W_lin, b_lin, coef, states, nullptr, nullptr, nullptr);
        chunk_scan_kernel<<<(B_*N_*H_)/256, 256, 0, stream>>>(states, coef, 512);
        gemm_scan_kernel<3,512><<<(B_*512)/4, 256, 0, stream>>>(
            x, W_lin, b_lin, coef, states, D, film, out);
    } else {
        coef_kernel<<<4, 256, 0, stream>>>(log_dt, A_re, A_im, C_re, C_im,
                                           coef, 128.0f);
        gemm_scan_kernel<1,256><<<(B_*256)/4, 256, 0, stream>>>(
            x, W_lin, b_lin, coef, states, nullptr, nullptr, nullptr);
        chunk_scan_kernel<<<(B_*N_*H_)/256, 256, 0, stream>>>(states, coef, 256);
        gemm_scan_kernel<3,256><<<(B_*256)/4, 256, 0, stream>>>(
            x, W_lin, b_lin, coef, states, D, film, out);
    }
}

// Round 7
// 495.371 us; speedup vs baseline: 1.3260x; 1.1099x over previous
//
#include <hip/hip_runtime.h>
#include <hip/hip_bf16.h>
#include <math.h>

#define B_ 16
#define L_ 32768
#define H_ 64
#define N_ 16
#define DM_ 32
#define TS_ 16   /* subtile rows */
#define US_ 68   /* uld row stride: 4*US_ ≡ 16 (mod 32) -> 2-way (free) write banks */
#define NG_ 8    /* scan groups per (b,n,h) */

typedef __attribute__((ext_vector_type(8))) short short8;
typedef __attribute__((ext_vector_type(4))) float floatx4;
typedef __attribute__((ext_vector_type(2))) float f32x2;

// gelu matching jax.nn.gelu(approximate=True)
__device__ __forceinline__ float fast_gelu(float v) {
    float z = fmaf(0.044715f * v, v * v, v) * 0.7978845608028654f;
#if __has_builtin(__builtin_amdgcn_exp2f) && __has_builtin(__builtin_amdgcn_rcpf)
    float e = __builtin_amdgcn_exp2f(z * 2.8853900817779268f);
    float t = 1.0f - 2.0f * __builtin_amdgcn_rcpf(e + 1.0f);
#else
    float t = tanhf(z);
#endif
    return 0.5f * v * (1.0f + t);
}

__device__ __forceinline__ unsigned short bf16_rne(float f) {
    unsigned u = __float_as_uint(f);
    return (unsigned short)((u + 0x7FFFu + ((u >> 16) & 1u)) >> 16);
}
__device__ __forceinline__ float bf16_tof(unsigned short h) {
    return __uint_as_float(((unsigned)h) << 16);
}
// split 8 floats into bf16 hi + bf16 lo fragments (packed)
__device__ __forceinline__ void cvt8(const float* f, short8* hi, short8* lo) {
    union { unsigned u[4]; short8 s; } Hh, Ll;
    #pragma unroll
    for (int jp = 0; jp < 4; ++jp) {
        unsigned short h0 = bf16_rne(f[2*jp]), h1 = bf16_rne(f[2*jp+1]);
        Hh.u[jp] = (unsigned)h0 | ((unsigned)h1 << 16);
        float l0 = f[2*jp]   - bf16_tof(h0);
        float l1 = f[2*jp+1] - bf16_tof(h1);
        Ll.u[jp] = (unsigned)bf16_rne(l0) | ((unsigned)bf16_rne(l1) << 16);
    }
    *hi = Hh.s; *lo = Ll.s;
}

// ---- packed complex scan step: s = w*s + (uv, 0) with w=(wr,wi), s=(sr,si) ----
// Bit-exact with: nr=fmaf(wr,sr,fmaf(-wi,si,uv)); ni=fmaf(wr,si,wi*sr)
__device__ __forceinline__ void pk_step(f32x2& s, f32x2 w, f32x2 uv0) {
    f32x2 t;
    asm("v_pk_fma_f32 %0, %1, %2, %3 op_sel:[1,1,0] op_sel_hi:[1,0,1] neg_lo:[1,0,0]"
        : "=v"(t) : "v"(w), "v"(s), "v"(uv0));
    asm("v_pk_fma_f32 %0, %1, %0, %2 op_sel_hi:[0,1,1]"
        : "+v"(s) : "v"(w), "v"(t));
}
// y += (c.lo*s.lo, c.hi*s.hi)
__device__ __forceinline__ void pk_acc(f32x2& y, f32x2 c, f32x2 s) {
    asm("v_pk_fma_f32 %0, %1, %2, %0"
        : "+v"(y) : "v"(c), "v"(s));
}

// ---------------- kernel 0a: cond MLP + FiLM params ----------------
__global__ void cond_film_kernel(const float* __restrict__ cp,
    const float* __restrict__ W0, const float* __restrict__ b0,
    const float* __restrict__ W1, const float* __restrict__ b1,
    const float* __restrict__ W2, const float* __restrict__ b2,
    const float* __restrict__ Wf, const float* __restrict__ bf,
    float* __restrict__ film) {
    __shared__ float ca[B_][DM_];
    __shared__ float cb[B_][DM_];
    int tid = threadIdx.x;            // 512 threads = 16 b * 32 j
    int b = tid >> 5, j = tid & 31;
    float acc = fmaf(cp[b*2+0], W0[j], fmaf(cp[b*2+1], W0[DM_+j], b0[j]));
    ca[b][j] = fast_gelu(acc);
    __syncthreads();
    acc = b1[j];
    #pragma unroll
    for (int i = 0; i < DM_; ++i) acc = fmaf(ca[b][i], W1[i*DM_+j], acc);
    cb[b][j] = fast_gelu(acc);
    __syncthreads();
    acc = b2[j];
    #pragma unroll
    for (int i = 0; i < DM_; ++i) acc = fmaf(cb[b][i], W2[i*DM_+j], acc);
    float c2 = fast_gelu(acc);
    __syncthreads();
    ca[b][j] = c2;
    __syncthreads();
    #pragma unroll
    for (int t = 0; t < 4; ++t) {
        int k = j + DM_*t;            // 0..127
        float a = bf[k];
        #pragma unroll
        for (int i = 0; i < DM_; ++i) a = fmaf(ca[b][i], Wf[i*2*H_+k], a);
        film[b*2*H_ + k] = a;         // [0:64)=gamma, [64:128)=beta
    }
}

// ---------------- kernel 0b: SSM coefficients ----------------
// coef layout: coef[(n*6+f)*H_ + h], f = {wr, wi, wTr, wTi, 2cr, 2ci}
__global__ void coef_kernel(const float* __restrict__ log_dt,
    const float* __restrict__ A_re, const float* __restrict__ A_im,
    const float* __restrict__ C_re, const float* __restrict__ C_im,
    float* __restrict__ coef, float Tf) {
    int g = blockIdx.x * blockDim.x + threadIdx.x;   // 1024
    if (g >= H_*N_) return;
    int h = g >> 4, n = g & 15;
    float dt = expf(log_dt[h]);
    float Ar = A_re[h*N_+n], Ai = A_im[h*N_+n];
    float ar = dt*Ar, ai = dt*Ai;
    float er = expf(ar);
    float wr = er * cosf(ai), wi = er * sinf(ai);
    float eT = expf(Tf * ar);
    float aT = Tf * ai;
    float wTr = eT * cosf(aT), wTi = eT * sinf(aT);
    float d  = Ar*Ar + Ai*Ai;
    float nr = wr - 1.0f, ni = wi;
    float qr = (nr*Ar + ni*Ai) / d;
    float qi = (ni*Ar - nr*Ai) / d;
    float Cr = C_re[h*N_+n], Ci = C_im[h*N_+n];
    float cr = 2.0f * (Cr*qr - Ci*qi);   // fold the 2*Re() factor in
    float ci = 2.0f * (Cr*qi + Ci*qr);
    coef[(n*6+0)*H_+h] = wr;
    coef[(n*6+1)*H_+h] = wi;
    coef[(n*6+2)*H_+h] = wTr;
    coef[(n*6+3)*H_+h] = wTi;
    coef[(n*6+4)*H_+h] = cr;
    coef[(n*6+5)*H_+h] = ci;
}

// ---------------- phase 2: grouped cross-chunk prefix (3 passes) ----------
// Old single-pass used 64 blocks (1/4 of CUs) for 134 MB -> ~84 us BW-bound.
// Split: NG_=8 groups of G chunks; passes 1&3 run 512 blocks (full width).
// states layout: states[(((b*Cc + c)*N_ + n)*H_ + h)*2]
// agg layout: agg float2[t], t = b*8192 + g*1024 + n*64 + h

// pass 1: group aggregates A_g (zero-init scan over G chunks, no writes to states)
__global__ void scan_agg_kernel(const float* __restrict__ states,
                                const float* __restrict__ coef,
                                float* __restrict__ agg, int Cc, int G) {
    int t = blockIdx.x * blockDim.x + threadIdx.x;  // B*NG*N*H = 131072
    int h = t & 63, n = (t >> 6) & 15, g = (t >> 10) & (NG_-1), b = t >> 13;
    float wTr = coef[(n*6+2)*H_+h], wTi = coef[(n*6+3)*H_+h];
    const float2* sp = (const float2*)states
        + ((size_t)(b*Cc + g*G))*N_*H_ + (size_t)n*H_ + h;
    const int stride = N_*H_;
    float car = 0.f, cai = 0.f;
    float2 buf[8];
    #pragma unroll
    for (int i = 0; i < 8; ++i) buf[i] = sp[(size_t)i*stride];
    for (int cg = 0; cg < G; cg += 8) {
        float2 nb[8];
        #pragma unroll
        for (int i = 0; i < 8; ++i)
            nb[i] = (cg + 8 + i < G) ? sp[(size_t)(cg+8+i)*stride]
                                     : make_float2(0.f, 0.f);
        #pragma unroll
        for (int i = 0; i < 8; ++i) {
            float2 v = buf[i];
            float nr2 = fmaf(wTr, car, fmaf(-wTi, cai, v.x));
            float ni2 = fmaf(wTr, cai, fmaf( wTi, car, v.y));
            car = nr2; cai = ni2;
            buf[i] = nb[i];
        }
    }
    ((float2*)agg)[t] = make_float2(car, cai);
}

// pass 2: scan the NG_ group carries; agg[g] <- exclusive prefix C_g
// C_{g+1} = wT^G * C_g + A_g  (wT^G via lg2G squarings)
__global__ void scan_group_kernel(float* __restrict__ agg,
                                  const float* __restrict__ coef, int lg2G) {
    int t = blockIdx.x * blockDim.x + threadIdx.x;  // B*N*H = 16384
    int h = t & 63, n = (t >> 6) & 15, b = t >> 10;
    float wr = coef[(n*6+2)*H_+h], wi = coef[(n*6+3)*H_+h];
    for (int i = 0; i < lg2G; ++i) {
        float nr = wr*wr - wi*wi, ni = 2.f*wr*wi;
        wr = nr; wi = ni;
    }
    float car = 0.f, cai = 0.f;
    float2* ap = (float2*)agg + (size_t)b*NG_*1024 + (size_t)n*64 + h;
    #pragma unroll
    for (int g = 0; g < NG_; ++g) {
        float2 v = ap[(size_t)g*1024];
        ap[(size_t)g*1024] = make_float2(car, cai);
        float nr = fmaf(wr, car, fmaf(-wi, cai, v.x));
        float ni = fmaf(wr, cai, fmaf( wi, car, v.y));
        car = nr; cai = ni;
    }
}

// pass 3: re-scan each group from its prefix C_g, writing exclusive prefixes
__global__ void scan_fix_kernel(float* __restrict__ states,
                                const float* __restrict__ coef,
                                const float* __restrict__ agg, int Cc, int G) {
    int t = blockIdx.x * blockDim.x + threadIdx.x;  // B*NG*N*H
    int h = t & 63, n = (t >> 6) & 15, g = (t >> 10) & (NG_-1), b = t >> 13;
    float wTr = coef[(n*6+2)*H_+h], wTi = coef[(n*6+3)*H_+h];
    float2* sp = (float2*)states
        + ((size_t)(b*Cc + g*G))*N_*H_ + (size_t)n*H_ + h;
    const int stride = N_*H_;
    float2 c0 = ((const float2*)agg)[t];
    float car = c0.x, cai = c0.y;
    float2 buf[8];
    #pragma unroll
    for (int i = 0; i < 8; ++i) buf[i] = sp[(size_t)i*stride];
    for (int cg = 0; cg < G; cg += 8) {
        float2 nb[8];
        #pragma unroll
        for (int i = 0; i < 8; ++i)
            nb[i] = (cg + 8 + i < G) ? sp[(size_t)(cg+8+i)*stride]
                                     : make_float2(0.f, 0.f);
        #pragma unroll
        for (int i = 0; i < 8; ++i) {
            float2 v = buf[i];
            sp[(size_t)(cg+i)*stride] = make_float2(car, cai);
            float nr2 = fmaf(wTr, car, fmaf(-wTi, cai, v.x));
            float ni2 = fmaf(wTr, cai, fmaf( wTi, car, v.y));
            car = nr2; cai = ni2;
            buf[i] = nb[i];
        }
    }
}

// ---------------- phases 1 & 3: MFMA GEMM + diagonal scan ----------------
// PHASE 1: zero-init states, write end-of-chunk local states.
// PHASE 3: init from prefix states, write final output (FiLM+gelu+gate fused).
// Round-2 design (measured best, 188 us phase-3): gate x staged through LDS
// from the A-load registers (physical reuse, no cache pressure). Register
// xg-prefetch was tried and REGRESSED (+134 MB HBM refetch: reuse distance
// spans a subtile x 12 resident waves -> L1/L2 thrash; measured round 6).
// __launch_bounds__(256,4) spills (~550 MB scratch, measured round 4).
template<int PHASE, int CC>
__global__ __launch_bounds__(256, 3)
void gemm_scan_kernel(const float* __restrict__ x,
                      const float* __restrict__ W_lin, const float* __restrict__ b_lin,
                      const float* __restrict__ coef, float* __restrict__ states,
                      const float* __restrict__ D, const float* __restrict__ film,
                      float* __restrict__ out) {
    constexpr int TT = L_/CC;                 // chunk length
    // W fragment table: frag f = (t*2+kt)*4+nt (t=0 hi, t=1 lo), 16 frags * 64 lanes * 16B
    __shared__ __align__(16) unsigned short Wf[16*64*8];     // 16 KB
    __shared__ float uld[4][TS_*US_];                         // 4 * 4.25 KB
    __shared__ float xld[(PHASE==3) ? 4*TS_*US_ : 4];         // phase-3 only: 17 KB
    const int lane = threadIdx.x & 63;
    const int wv   = threadIdx.x >> 6;
    const int q    = blockIdx.x*4 + wv;        // chunk id 0..B_*CC-1
    const int b    = q / CC;
    const int c    = q % CC;
    const int m    = lane & 15;
    const int quad = lane >> 4;

    // ---- build W fragments in LDS (each wave writes full table; identical values,
    //      so no barrier needed — per-wave DS ordering covers own writes) ----
    for (int kt = 0; kt < 2; ++kt)
        for (int nt = 0; nt < 4; ++nt) {
            float f[8];
            #pragma unroll
            for (int j = 0; j < 8; ++j)
                f[j] = W_lin[(kt*32 + quad*8 + j)*H_ + nt*16 + m];
            short8 hi, lo;
            cvt8(f, &hi, &lo);
            ((short8*)Wf)[(kt*4 + nt)*64 + lane]     = hi;   // t=0
            ((short8*)Wf)[((2+kt)*4 + nt)*64 + lane] = lo;   // t=1
        }

    // ---- scan coefficients / state init (packed pairs) ----
    f32x2 w2[N_], s2[N_], c2[N_];
    float g_ = 0.f, be_ = 0.f, Dh = 0.f;
    #pragma unroll
    for (int n = 0; n < N_; ++n) {
        w2[n].x = coef[(n*6+0)*H_ + lane];
        w2[n].y = coef[(n*6+1)*H_ + lane];
    }
    if (PHASE == 1) {
        #pragma unroll
        for (int n = 0; n < N_; ++n) s2[n] = (f32x2){0.f, 0.f};
    } else {
        #pragma unroll
        for (int n = 0; n < N_; ++n) {
            c2[n].x = coef[(n*6+4)*H_ + lane];
            c2[n].y = coef[(n*6+5)*H_ + lane];
            size_t idx = (((size_t)q*N_ + n)*H_ + lane)*2;
            s2[n] = *(const f32x2*)(states + idx);
        }
        g_  = film[b*2*H_ + lane];
        be_ = film[b*2*H_ + H_ + lane];
        Dh  = D[lane];
    }
    float blv[4];
    #pragma unroll
    for (int nt = 0; nt < 4; ++nt) blv[nt] = b_lin[nt*16 + m];

    const float* xp = x + ((size_t)b*L_ + (size_t)c*TT)*H_;
    float* op = out + ((size_t)b*L_ + (size_t)c*TT)*H_;
    float* myu = uld[wv];
    float* myx = (PHASE==3) ? &xld[wv*TS_*US_] : nullptr;

    for (int s = 0; s < TT/TS_; ++s) {
        const float* xs = xp + s*TS_*H_;
        // A fragments straight from global: A[m=lane&15][k=kt*32+quad*8+j]
        short8 ah[2], al[2];
        #pragma unroll
        for (int kt = 0; kt < 2; ++kt) {
            const float* src = xs + m*H_ + kt*32 + quad*8;
            float4 v0 = *(const float4*)(src);
            float4 v1 = *(const float4*)(src + 4);
            if (PHASE == 3) {
                // stage x for the gate read (transpose consumed via LDS)
                float* dst = &myx[m*US_ + kt*32 + quad*8];
                *(float4*)(dst)     = v0;
                *(float4*)(dst + 4) = v1;
            }
            float f[8] = {v0.x, v0.y, v0.z, v0.w, v1.x, v1.y, v1.z, v1.w};
            cvt8(f, &ah[kt], &al[kt]);
        }
        // MFMA + epilogue: gelu, transpose u through LDS (row stride US_)
        #pragma unroll
        for (int nt = 0; nt < 4; ++nt) {
            floatx4 acc = {0.f, 0.f, 0.f, 0.f};
            #pragma unroll
            for (int kt = 0; kt < 2; ++kt) {
                short8 bh = ((short8*)Wf)[(kt*4 + nt)*64 + lane];
                short8 bl = ((short8*)Wf)[((2+kt)*4 + nt)*64 + lane];
                acc = __builtin_amdgcn_mfma_f32_16x16x32_bf16(ah[kt], bh, acc, 0, 0, 0);
                acc = __builtin_amdgcn_mfma_f32_16x16x32_bf16(al[kt], bh, acc, 0, 0, 0);
                acc = __builtin_amdgcn_mfma_f32_16x16x32_bf16(ah[kt], bl, acc, 0, 0, 0);
            }
            // C layout: col = nt*16 + (lane&15), row = quad*4 + reg
            #pragma unroll
            for (int r = 0; r < 4; ++r) {
                int row = quad*4 + r;
                float uv = fast_gelu(acc[r] + blv[nt]);
                myu[row*US_ + nt*16 + m] = uv;
            }
        }
        // scan TS_ rows (lane = h); software-pipelined LDS reads (depth 1)
        float uvc = myu[lane];
        float xgc = (PHASE==3) ? myx[lane] : 0.f;
        for (int l = 0; l < TS_; ++l) {
            int ln = (l+1) & (TS_-1);            // row 0 re-read on last iter (harmless)
            float uvn = myu[ln*US_ + lane];
            float xgn = (PHASE==3) ? myx[ln*US_ + lane] : 0.f;
            f32x2 uv0 = {uvc, 0.f};
            if (PHASE == 1) {
                #pragma unroll
                for (int n = 0; n < N_; ++n) pk_step(s2[n], w2[n], uv0);
            } else {
                f32x2 y2 = {0.f, 0.f};
                #pragma unroll
                for (int n = 0; n < N_; ++n) {
                    pk_step(s2[n], w2[n], uv0);
                    pk_acc(y2, c2[n], s2[n]);
                }
                float y  = fmaf(Dh, uvc, y2.x - y2.y);  // conv + D*u
                float yg = fast_gelu(fmaf(y, g_, be_)); // FiLM + gelu
                op[(s*TS_ + l)*H_ + lane] = xgc * yg;   // side-chain gate
            }
            uvc = uvn; xgc = xgn;
        }
    }
    if (PHASE == 1) {
        #pragma unroll
        for (int n = 0; n < N_; ++n) {
            size_t idx = (((size_t)q*N_ + n)*H_ + lane)*2;
            *(f32x2*)(states + idx) = s2[n];
        }
    }
}

extern "C" void kernel_launch(void* const* d_in, const int* in_sizes, int n_in,
                              void* d_out, int out_size, void* d_ws, size_t ws_size,
                              hipStream_t stream) {
    const float* x     = (const float*)d_in[0];
    const float* cp    = (const float*)d_in[1];
    const float* W0    = (const float*)d_in[2];
    const float* b0    = (const float*)d_in[3];
    const float* W1    = (const float*)d_in[4];
    const float* b1    = (const float*)d_in[5];
    const float* W2    = (const float*)d_in[6];
    const float* b2    = (const float*)d_in[7];
    const float* W_lin = (const float*)d_in[8];
    const float* b_lin = (const float*)d_in[9];
    const float* log_dt= (const float*)d_in[10];
    const float* A_re  = (const float*)d_in[11];
    const float* A_im  = (const float*)d_in[12];
    const float* C_re  = (const float*)d_in[13];
    const float* C_im  = (const float*)d_in[14];
    const float* D     = (const float*)d_in[15];
    const float* W_f   = (const float*)d_in[16];
    const float* b_f   = (const float*)d_in[17];
    float* out = (float*)d_out;

    float* film   = (float*)d_ws;                  // B*2H       = 2048 floats
    float* coef   = film + B_*2*H_;                // 6*H*N      = 6144 floats
    float* states = coef + 6*H_*N_;                // B*Cc*N*H*2 floats

    cond_film_kernel<<<1, 512, 0, stream>>>(cp, W0, b0, W1, b1, W2, b2,
                                            W_f, b_f, film);

    // T-split: prefer 64-length chunks (2x parallelism) if workspace allows.
    size_t need64 = (size_t)(B_*2*H_ + 6*H_*N_)*4
                  + (size_t)B_*512*N_*H_*2*4            // states ~64 MiB
                  + (size_t)B_*NG_*N_*H_*2*4;           // agg ~1 MiB
    if (ws_size >= need64) {
        const int Cc = 512, G = 64, lg2G = 6;
        float* agg = states + (size_t)B_*Cc*N_*H_*2;
        coef_kernel<<<4, 256, 0, stream>>>(log_dt, A_re, A_im, C_re, C_im,
                                           coef, (float)(L_/Cc));
        gemm_scan_kernel<1,512><<<(B_*512)/4, 256, 0, stream>>>(
            x, W_lin, b_lin, coef, states, nullptr, nullptr, nullptr);
        scan_agg_kernel<<<(B_*NG_*N_*H_)/256, 256, 0, stream>>>(states, coef,
                                                                agg, Cc, G);
        scan_group_kernel<<<(B_*N_*H_)/256, 256, 0, stream>>>(agg, coef, lg2G);
        scan_fix_kernel<<<(B_*NG_*N_*H_)/256, 256, 0, stream>>>(states, coef,
                                                                agg, Cc, G);
        gemm_scan_kernel<3,512><<<(B_*512)/4, 256, 0, stream>>>(
            x, W_lin, b_lin, coef, states, D, film, out);
    } else {
        const int Cc = 256, G = 32, lg2G = 5;
        float* agg = states + (size_t)B_*Cc*N_*H_*2;
        coef_kernel<<<4, 256, 0, stream>>>(log_dt, A_re, A_im, C_re, C_im,
                                           coef, (float)(L_/Cc));
        gemm_scan_kernel<1,256><<<(B_*256)/4, 256, 0, stream>>>(
            x, W_lin, b_lin, coef, states, nullptr, nullptr, nullptr);
        scan_agg_kernel<<<(B_*NG_*N_*H_)/256, 256, 0, stream>>>(states, coef,
                                                                agg, Cc, G);
        scan_group_kernel<<<(B_*N_*H_)/256, 256, 0, stream>>>(agg, coef, lg2G);
        scan_fix_kernel<<<(B_*NG_*N_*H_)/256, 256, 0, stream>>>(states, coef,
                                                                agg, Cc, G);
        gemm_scan_kernel<3,256><<<(B_*256)/4, 256, 0, stream>>>(
            x, W_lin, b_lin, coef, states, D, film, out);
    }
}

// Round 9
// 440.416 us; speedup vs baseline: 1.4915x; 1.1248x over previous
//
#include <hip/hip_runtime.h>
#include <hip/hip_bf16.h>
#include <math.h>

#define B_ 16
#define L_ 32768
#define H_ 64
#define N_ 16
#define DM_ 32
#define TS_ 16   /* subtile rows */
#define US_ 68   /* uld row stride: 4*US_ ≡ 16 (mod 32) -> 2-way (free) write banks */
#define NG_ 8    /* scan groups per (b,n,h) */

typedef __attribute__((ext_vector_type(8))) short short8;
typedef __attribute__((ext_vector_type(4))) float floatx4;
typedef __attribute__((ext_vector_type(2))) float f32x2;

// gelu matching jax.nn.gelu(approximate=True)
__device__ __forceinline__ float fast_gelu(float v) {
    float z = fmaf(0.044715f * v, v * v, v) * 0.7978845608028654f;
#if __has_builtin(__builtin_amdgcn_exp2f) && __has_builtin(__builtin_amdgcn_rcpf)
    float e = __builtin_amdgcn_exp2f(z * 2.8853900817779268f);
    float t = 1.0f - 2.0f * __builtin_amdgcn_rcpf(e + 1.0f);
#else
    float t = tanhf(z);
#endif
    return 0.5f * v * (1.0f + t);
}

__device__ __forceinline__ unsigned short bf16_rne(float f) {
    unsigned u = __float_as_uint(f);
    return (unsigned short)((u + 0x7FFFu + ((u >> 16) & 1u)) >> 16);
}
__device__ __forceinline__ float bf16_tof(unsigned short h) {
    return __uint_as_float(((unsigned)h) << 16);
}
// split 8 floats into bf16 hi + bf16 lo fragments (packed)
__device__ __forceinline__ void cvt8(const float* f, short8* hi, short8* lo) {
    union { unsigned u[4]; short8 s; } Hh, Ll;
    #pragma unroll
    for (int jp = 0; jp < 4; ++jp) {
        unsigned short h0 = bf16_rne(f[2*jp]), h1 = bf16_rne(f[2*jp+1]);
        Hh.u[jp] = (unsigned)h0 | ((unsigned)h1 << 16);
        float l0 = f[2*jp]   - bf16_tof(h0);
        float l1 = f[2*jp+1] - bf16_tof(h1);
        Ll.u[jp] = (unsigned)bf16_rne(l0) | ((unsigned)bf16_rne(l1) << 16);
    }
    *hi = Hh.s; *lo = Ll.s;
}

// ---- packed complex scan step: s = w*s + (uv, 0) with w=(wr,wi), s=(sr,si) ----
// Bit-exact with: nr=fmaf(wr,sr,fmaf(-wi,si,uv)); ni=fmaf(wr,si,wi*sr)
__device__ __forceinline__ void pk_step(f32x2& s, f32x2 w, f32x2 uv0) {
    f32x2 t;
    asm("v_pk_fma_f32 %0, %1, %2, %3 op_sel:[1,1,0] op_sel_hi:[1,0,1] neg_lo:[1,0,0]"
        : "=v"(t) : "v"(w), "v"(s), "v"(uv0));
    asm("v_pk_fma_f32 %0, %1, %0, %2 op_sel_hi:[0,1,1]"
        : "+v"(s) : "v"(w), "v"(t));
}
// y += (c.lo*s.lo, c.hi*s.hi)
__device__ __forceinline__ void pk_acc(f32x2& y, f32x2 c, f32x2 s) {
    asm("v_pk_fma_f32 %0, %1, %2, %0"
        : "+v"(y) : "v"(c), "v"(s));
}

// ---------------- kernel 0a: cond MLP + FiLM params ----------------
__global__ void cond_film_kernel(const float* __restrict__ cp,
    const float* __restrict__ W0, const float* __restrict__ b0,
    const float* __restrict__ W1, const float* __restrict__ b1,
    const float* __restrict__ W2, const float* __restrict__ b2,
    const float* __restrict__ Wf, const float* __restrict__ bf,
    float* __restrict__ film) {
    __shared__ float ca[B_][DM_];
    __shared__ float cb[B_][DM_];
    int tid = threadIdx.x;            // 512 threads = 16 b * 32 j
    int b = tid >> 5, j = tid & 31;
    float acc = fmaf(cp[b*2+0], W0[j], fmaf(cp[b*2+1], W0[DM_+j], b0[j]));
    ca[b][j] = fast_gelu(acc);
    __syncthreads();
    acc = b1[j];
    #pragma unroll
    for (int i = 0; i < DM_; ++i) acc = fmaf(ca[b][i], W1[i*DM_+j], acc);
    cb[b][j] = fast_gelu(acc);
    __syncthreads();
    acc = b2[j];
    #pragma unroll
    for (int i = 0; i < DM_; ++i) acc = fmaf(cb[b][i], W2[i*DM_+j], acc);
    float c2 = fast_gelu(acc);
    __syncthreads();
    ca[b][j] = c2;
    __syncthreads();
    #pragma unroll
    for (int t = 0; t < 4; ++t) {
        int k = j + DM_*t;            // 0..127
        float a = bf[k];
        #pragma unroll
        for (int i = 0; i < DM_; ++i) a = fmaf(ca[b][i], Wf[i*2*H_+k], a);
        film[b*2*H_ + k] = a;         // [0:64)=gamma, [64:128)=beta
    }
}

// ---------------- kernel 0b: SSM coefficients ----------------
// coef layout: coef[(n*6+f)*H_ + h], f = {wr, wi, wTr, wTi, 2cr, 2ci}
__global__ void coef_kernel(const float* __restrict__ log_dt,
    const float* __restrict__ A_re, const float* __restrict__ A_im,
    const float* __restrict__ C_re, const float* __restrict__ C_im,
    float* __restrict__ coef, float Tf) {
    int g = blockIdx.x * blockDim.x + threadIdx.x;   // 1024
    if (g >= H_*N_) return;
    int h = g >> 4, n = g & 15;
    float dt = expf(log_dt[h]);
    float Ar = A_re[h*N_+n], Ai = A_im[h*N_+n];
    float ar = dt*Ar, ai = dt*Ai;
    float er = expf(ar);
    float wr = er * cosf(ai), wi = er * sinf(ai);
    float eT = expf(Tf * ar);
    float aT = Tf * ai;
    float wTr = eT * cosf(aT), wTi = eT * sinf(aT);
    float d  = Ar*Ar + Ai*Ai;
    float nr = wr - 1.0f, ni = wi;
    float qr = (nr*Ar + ni*Ai) / d;
    float qi = (ni*Ar - nr*Ai) / d;
    float Cr = C_re[h*N_+n], Ci = C_im[h*N_+n];
    float cr = 2.0f * (Cr*qr - Ci*qi);   // fold the 2*Re() factor in
    float ci = 2.0f * (Cr*qi + Ci*qr);
    coef[(n*6+0)*H_+h] = wr;
    coef[(n*6+1)*H_+h] = wi;
    coef[(n*6+2)*H_+h] = wTr;
    coef[(n*6+3)*H_+h] = wTi;
    coef[(n*6+4)*H_+h] = cr;
    coef[(n*6+5)*H_+h] = ci;
}

// ---------------- phase 2: grouped cross-chunk prefix (3 passes) ----------
// states layout: states[(((b*Cc + c)*N_ + n)*H_ + h)*2]
// agg layout: agg float2[t], t = b*8192 + g*1024 + n*64 + h

__global__ void scan_agg_kernel(const float* __restrict__ states,
                                const float* __restrict__ coef,
                                float* __restrict__ agg, int Cc, int G) {
    int t = blockIdx.x * blockDim.x + threadIdx.x;  // B*NG*N*H = 131072
    int h = t & 63, n = (t >> 6) & 15, g = (t >> 10) & (NG_-1), b = t >> 13;
    float wTr = coef[(n*6+2)*H_+h], wTi = coef[(n*6+3)*H_+h];
    const float2* sp = (const float2*)states
        + ((size_t)(b*Cc + g*G))*N_*H_ + (size_t)n*H_ + h;
    const int stride = N_*H_;
    float car = 0.f, cai = 0.f;
    float2 buf[8];
    #pragma unroll
    for (int i = 0; i < 8; ++i) buf[i] = sp[(size_t)i*stride];
    for (int cg = 0; cg < G; cg += 8) {
        float2 nb[8];
        #pragma unroll
        for (int i = 0; i < 8; ++i)
            nb[i] = (cg + 8 + i < G) ? sp[(size_t)(cg+8+i)*stride]
                                     : make_float2(0.f, 0.f);
        #pragma unroll
        for (int i = 0; i < 8; ++i) {
            float2 v = buf[i];
            float nr2 = fmaf(wTr, car, fmaf(-wTi, cai, v.x));
            float ni2 = fmaf(wTr, cai, fmaf( wTi, car, v.y));
            car = nr2; cai = ni2;
            buf[i] = nb[i];
        }
    }
    ((float2*)agg)[t] = make_float2(car, cai);
}

__global__ void scan_group_kernel(float* __restrict__ agg,
                                  const float* __restrict__ coef, int lg2G) {
    int t = blockIdx.x * blockDim.x + threadIdx.x;  // B*N*H = 16384
    int h = t & 63, n = (t >> 6) & 15, b = t >> 10;
    float wr = coef[(n*6+2)*H_+h], wi = coef[(n*6+3)*H_+h];
    for (int i = 0; i < lg2G; ++i) {
        float nr = wr*wr - wi*wi, ni = 2.f*wr*wi;
        wr = nr; wi = ni;
    }
    float car = 0.f, cai = 0.f;
    float2* ap = (float2*)agg + (size_t)b*NG_*1024 + (size_t)n*64 + h;
    #pragma unroll
    for (int g = 0; g < NG_; ++g) {
        float2 v = ap[(size_t)g*1024];
        ap[(size_t)g*1024] = make_float2(car, cai);
        float nr = fmaf(wr, car, fmaf(-wi, cai, v.x));
        float ni = fmaf(wr, cai, fmaf( wi, car, v.y));
        car = nr; cai = ni;
    }
}

__global__ void scan_fix_kernel(float* __restrict__ states,
                                const float* __restrict__ coef,
                                const float* __restrict__ agg, int Cc, int G) {
    int t = blockIdx.x * blockDim.x + threadIdx.x;  // B*NG*N*H
    int h = t & 63, n = (t >> 6) & 15, g = (t >> 10) & (NG_-1), b = t >> 13;
    float wTr = coef[(n*6+2)*H_+h], wTi = coef[(n*6+3)*H_+h];
    float2* sp = (float2*)states
        + ((size_t)(b*Cc + g*G))*N_*H_ + (size_t)n*H_ + h;
    const int stride = N_*H_;
    float2 c0 = ((const float2*)agg)[t];
    float car = c0.x, cai = c0.y;
    float2 buf[8];
    #pragma unroll
    for (int i = 0; i < 8; ++i) buf[i] = sp[(size_t)i*stride];
    for (int cg = 0; cg < G; cg += 8) {
        float2 nb[8];
        #pragma unroll
        for (int i = 0; i < 8; ++i)
            nb[i] = (cg + 8 + i < G) ? sp[(size_t)(cg+8+i)*stride]
                                     : make_float2(0.f, 0.f);
        #pragma unroll
        for (int i = 0; i < 8; ++i) {
            float2 v = buf[i];
            sp[(size_t)(cg+i)*stride] = make_float2(car, cai);
            float nr2 = fmaf(wTr, car, fmaf(-wTi, cai, v.x));
            float ni2 = fmaf(wTr, cai, fmaf( wTi, car, v.y));
            car = nr2; cai = ni2;
            buf[i] = nb[i];
        }
    }
}

// ---------------- phases 1 & 3: MFMA GEMM + diagonal scan ----------------
// PHASE 1: zero-init states, write end-of-chunk local states.
//   UST=true additionally streams u (fp32, [t][h] coalesced) to ubuf so the
//   lean scan_out kernel can skip the whole GEMM (u computed ONCE).
// PHASE 3 (fallback only): fused output with LDS-staged gate.
// __launch_bounds__(256,4) spills (~550 MB scratch, measured round 4).
// xg-in-registers refetches x from HBM (+134 MB, measured round 6).
template<int PHASE, int CC, bool UST>
__global__ __launch_bounds__(256, 3)
void gemm_scan_kernel(const float* __restrict__ x,
                      const float* __restrict__ W_lin, const float* __restrict__ b_lin,
                      const float* __restrict__ coef, float* __restrict__ states,
                      const float* __restrict__ D, const float* __restrict__ film,
                      float* __restrict__ out, float* __restrict__ ubuf) {
    constexpr int TT = L_/CC;                 // chunk length
    __shared__ __align__(16) unsigned short Wf[16*64*8];     // 16 KB
    __shared__ float uld[4][TS_*US_];                         // 4 * 4.25 KB
    __shared__ float xld[(PHASE==3) ? 4*TS_*US_ : 4];         // phase-3 only: 17 KB
    const int lane = threadIdx.x & 63;
    const int wv   = threadIdx.x >> 6;
    const int q    = blockIdx.x*4 + wv;        // chunk id 0..B_*CC-1
    const int b    = q / CC;
    const int c    = q % CC;
    const int m    = lane & 15;
    const int quad = lane >> 4;

    for (int kt = 0; kt < 2; ++kt)
        for (int nt = 0; nt < 4; ++nt) {
            float f[8];
            #pragma unroll
            for (int j = 0; j < 8; ++j)
                f[j] = W_lin[(kt*32 + quad*8 + j)*H_ + nt*16 + m];
            short8 hi, lo;
            cvt8(f, &hi, &lo);
            ((short8*)Wf)[(kt*4 + nt)*64 + lane]     = hi;   // t=0
            ((short8*)Wf)[((2+kt)*4 + nt)*64 + lane] = lo;   // t=1
        }

    f32x2 w2[N_], s2[N_], c2[N_];
    float g_ = 0.f, be_ = 0.f, Dh = 0.f;
    #pragma unroll
    for (int n = 0; n < N_; ++n) {
        w2[n].x = coef[(n*6+0)*H_ + lane];
        w2[n].y = coef[(n*6+1)*H_ + lane];
    }
    if (PHASE == 1) {
        #pragma unroll
        for (int n = 0; n < N_; ++n) s2[n] = (f32x2){0.f, 0.f};
    } else {
        #pragma unroll
        for (int n = 0; n < N_; ++n) {
            c2[n].x = coef[(n*6+4)*H_ + lane];
            c2[n].y = coef[(n*6+5)*H_ + lane];
            size_t idx = (((size_t)q*N_ + n)*H_ + lane)*2;
            s2[n] = *(const f32x2*)(states + idx);
        }
        g_  = film[b*2*H_ + lane];
        be_ = film[b*2*H_ + H_ + lane];
        Dh  = D[lane];
    }
    float blv[4];
    #pragma unroll
    for (int nt = 0; nt < 4; ++nt) blv[nt] = b_lin[nt*16 + m];

    const size_t base = ((size_t)b*L_ + (size_t)c*TT)*H_;
    const float* xp = x + base;
    float* op = out + base;
    float* ubp = UST ? (ubuf + base) : nullptr;
    float* myu = uld[wv];
    float* myx = (PHASE==3) ? &xld[wv*TS_*US_] : nullptr;

    for (int s = 0; s < TT/TS_; ++s) {
        const float* xs = xp + s*TS_*H_;
        short8 ah[2], al[2];
        #pragma unroll
        for (int kt = 0; kt < 2; ++kt) {
            const float* src = xs + m*H_ + kt*32 + quad*8;
            float4 v0 = *(const float4*)(src);
            float4 v1 = *(const float4*)(src + 4);
            if (PHASE == 3) {
                float* dst = &myx[m*US_ + kt*32 + quad*8];
                *(float4*)(dst)     = v0;
                *(float4*)(dst + 4) = v1;
            }
            float f[8] = {v0.x, v0.y, v0.z, v0.w, v1.x, v1.y, v1.z, v1.w};
            cvt8(f, &ah[kt], &al[kt]);
        }
        #pragma unroll
        for (int nt = 0; nt < 4; ++nt) {
            floatx4 acc = {0.f, 0.f, 0.f, 0.f};
            #pragma unroll
            for (int kt = 0; kt < 2; ++kt) {
                short8 bh = ((short8*)Wf)[(kt*4 + nt)*64 + lane];
                short8 bl = ((short8*)Wf)[((2+kt)*4 + nt)*64 + lane];
                acc = __builtin_amdgcn_mfma_f32_16x16x32_bf16(ah[kt], bh, acc, 0, 0, 0);
                acc = __builtin_amdgcn_mfma_f32_16x16x32_bf16(al[kt], bh, acc, 0, 0, 0);
                acc = __builtin_amdgcn_mfma_f32_16x16x32_bf16(ah[kt], bl, acc, 0, 0, 0);
            }
            #pragma unroll
            for (int r = 0; r < 4; ++r) {
                int row = quad*4 + r;
                float uv = fast_gelu(acc[r] + blv[nt]);
                myu[row*US_ + nt*16 + m] = uv;
            }
        }
        // scan TS_ rows (lane = h); software-pipelined LDS reads (depth 1)
        float uvc = myu[lane];
        float xgc = (PHASE==3) ? myx[lane] : 0.f;
        for (int l = 0; l < TS_; ++l) {
            int ln = (l+1) & (TS_-1);
            float uvn = myu[ln*US_ + lane];
            float xgn = (PHASE==3) ? myx[ln*US_ + lane] : 0.f;
            f32x2 uv0 = {uvc, 0.f};
            if (PHASE == 1) {
                if (UST) ubp[(s*TS_ + l)*H_ + lane] = uvc;   // coalesced u stream
                #pragma unroll
                for (int n = 0; n < N_; ++n) pk_step(s2[n], w2[n], uv0);
            } else {
                f32x2 y2 = {0.f, 0.f};
                #pragma unroll
                for (int n = 0; n < N_; ++n) {
                    pk_step(s2[n], w2[n], uv0);
                    pk_acc(y2, c2[n], s2[n]);
                }
                float y  = fmaf(Dh, uvc, y2.x - y2.y);
                float yg = fast_gelu(fmaf(y, g_, be_));
                op[(s*TS_ + l)*H_ + lane] = xgc * yg;
            }
            uvc = uvn; xgc = xgn;
        }
    }
    if (PHASE == 1) {
        #pragma unroll
        for (int n = 0; n < N_; ++n) {
            size_t idx = (((size_t)q*N_ + n)*H_ + lane)*2;
            *(f32x2*)(states + idx) = s2[n];
        }
    }
}

// ---------------- phase 3 (lean): streaming scan + output ----------------
// No LDS, no MFMA: per l, 2 coalesced loads (u,x) + 48 v_pk_fma + store.
// Loads batched 8-deep with next-batch prefetch.
template<int CC>
__global__ __launch_bounds__(256, 3)
void scan_out_kernel(const float* __restrict__ u, const float* __restrict__ x,
                     const float* __restrict__ coef, const float* __restrict__ states,
                     const float* __restrict__ D, const float* __restrict__ film,
                     float* __restrict__ out) {
    constexpr int TT = L_/CC;
    constexpr int BL = 8;
    const int lane = threadIdx.x & 63;
    const int wv   = threadIdx.x >> 6;
    const int q    = blockIdx.x*4 + wv;
    const int b    = q / CC;
    f32x2 w2[N_], s2[N_], c2[N_];
    #pragma unroll
    for (int n = 0; n < N_; ++n) {
        w2[n].x = coef[(n*6+0)*H_ + lane];
        w2[n].y = coef[(n*6+1)*H_ + lane];
        c2[n].x = coef[(n*6+4)*H_ + lane];
        c2[n].y = coef[(n*6+5)*H_ + lane];
        size_t idx = (((size_t)q*N_ + n)*H_ + lane)*2;
        s2[n] = *(const f32x2*)(states + idx);
    }
    const float g_  = film[b*2*H_ + lane];
    const float be_ = film[b*2*H_ + H_ + lane];
    const float Dh  = D[lane];
    const size_t base = ((size_t)b*L_ + (size_t)(q % CC)*TT)*H_;
    const float* up = u + base;
    const float* xp = x + base;
    float* op = out + base;

    float ub[BL], xb[BL];
    #pragma unroll
    for (int i = 0; i < BL; ++i) {
        ub[i] = up[i*H_ + lane];
        xb[i] = xp[i*H_ + lane];
    }
    for (int t0 = 0; t0 < TT; t0 += BL) {
        float nu[BL] = {}, nx[BL] = {};
        if (t0 + BL < TT) {
            #pragma unroll
            for (int i = 0; i < BL; ++i) {
                nu[i] = up[(t0+BL+i)*H_ + lane];
                nx[i] = xp[(t0+BL+i)*H_ + lane];
            }
        }
        #pragma unroll
        for (int i = 0; i < BL; ++i) {
            f32x2 uv0 = {ub[i], 0.f};
            f32x2 y2 = {0.f, 0.f};
            #pragma unroll
            for (int n = 0; n < N_; ++n) {
                pk_step(s2[n], w2[n], uv0);
                pk_acc(y2, c2[n], s2[n]);
            }
            float y  = fmaf(Dh, ub[i], y2.x - y2.y);
            float yg = fast_gelu(fmaf(y, g_, be_));
            op[(t0+i)*H_ + lane] = xb[i] * yg;
            ub[i] = nu[i]; xb[i] = nx[i];
        }
    }
}

extern "C" void kernel_launch(void* const* d_in, const int* in_sizes, int n_in,
                              void* d_out, int out_size, void* d_ws, size_t ws_size,
                              hipStream_t stream) {
    const float* x     = (const float*)d_in[0];
    const float* cp    = (const float*)d_in[1];
    const float* W0    = (const float*)d_in[2];
    const float* b0    = (const float*)d_in[3];
    const float* W1    = (const float*)d_in[4];
    const float* b1    = (const float*)d_in[5];
    const float* W2    = (const float*)d_in[6];
    const float* b2    = (const float*)d_in[7];
    const float* W_lin = (const float*)d_in[8];
    const float* b_lin = (const float*)d_in[9];
    const float* log_dt= (const float*)d_in[10];
    const float* A_re  = (const float*)d_in[11];
    const float* A_im  = (const float*)d_in[12];
    const float* C_re  = (const float*)d_in[13];
    const float* C_im  = (const float*)d_in[14];
    const float* D     = (const float*)d_in[15];
    const float* W_f   = (const float*)d_in[16];
    const float* b_f   = (const float*)d_in[17];
    float* out = (float*)d_out;

    float* film   = (float*)d_ws;                  // B*2H       = 2048 floats
    float* coef   = film + B_*2*H_;                // 6*H*N      = 6144 floats
    float* states = coef + 6*H_*N_;                // B*Cc*N*H*2 floats

    cond_film_kernel<<<1, 512, 0, stream>>>(cp, W0, b0, W1, b1, W2, b2,
                                            W_f, b_f, film);

    const size_t head = (size_t)(B_*2*H_ + 6*H_*N_);
    const size_t st512 = (size_t)B_*512*N_*H_*2;       // 16.8M floats
    const size_t aggsz = (size_t)B_*NG_*N_*H_*2;       // 262k floats
    const size_t usz   = (size_t)B_*L_*H_;             // 33.6M floats
    size_t need_u  = (head + st512 + aggsz + usz)*4;   // ~203 MiB
    size_t need64  = (head + st512 + aggsz)*4;         // ~68 MiB

    if (ws_size >= need_u) {
        const int Cc = 512, G = 64, lg2G = 6;
        float* agg  = states + st512;
        float* ubuf = agg + aggsz;
        coef_kernel<<<4, 256, 0, stream>>>(log_dt, A_re, A_im, C_re, C_im,
                                           coef, (float)(L_/Cc));
        gemm_scan_kernel<1,512,true><<<(B_*512)/4, 256, 0, stream>>>(
            x, W_lin, b_lin, coef, states, nullptr, nullptr, nullptr, ubuf);
        scan_agg_kernel<<<(B_*NG_*N_*H_)/256, 256, 0, stream>>>(states, coef,
                                                                agg, Cc, G);
        scan_group_kernel<<<(B_*N_*H_)/256, 256, 0, stream>>>(agg, coef, lg2G);
        scan_fix_kernel<<<(B_*NG_*N_*H_)/256, 256, 0, stream>>>(states, coef,
                                                                agg, Cc, G);
        scan_out_kernel<512><<<(B_*512)/4, 256, 0, stream>>>(
            ubuf, x, coef, states, D, film, out);
    } else if (ws_size >= need64) {
        const int Cc = 512, G = 64, lg2G = 6;
        float* agg = states + st512;
        coef_kernel<<<4, 256, 0, stream>>>(log_dt, A_re, A_im, C_re, C_im,
                                           coef, (float)(L_/Cc));
        gemm_scan_kernel<1,512,false><<<(B_*512)/4, 256, 0, stream>>>(
            x, W_lin, b_lin, coef, states, nullptr, nullptr, nullptr, nullptr);
        scan_agg_kernel<<<(B_*NG_*N_*H_)/256, 256, 0, stream>>>(states, coef,
                                                                agg, Cc, G);
        scan_group_kernel<<<(B_*N_*H_)/256, 256, 0, stream>>>(agg, coef, lg2G);
        scan_fix_kernel<<<(B_*NG_*N_*H_)/256, 256, 0, stream>>>(states, coef,
                                                                agg, Cc, G);
        gemm_scan_kernel<3,512,false><<<(B_*512)/4, 256, 0, stream>>>(
            x, W_lin, b_lin, coef, states, D, film, out, nullptr);
    } else {
        const int Cc = 256, G = 32, lg2G = 5;
        float* agg = states + (size_t)B_*256*N_*H_*2;
        coef_kernel<<<4, 256, 0, stream>>>(log_dt, A_re, A_im, C_re, C_im,
                                           coef, (float)(L_/Cc));
        gemm_scan_kernel<1,256,false><<<(B_*256)/4, 256, 0, stream>>>(
            x, W_lin, b_lin, coef, states, nullptr, nullptr, nullptr, nullptr);
        scan_agg_kernel<<<(B_*NG_*N_*H_)/256, 256, 0, stream>>>(states, coef,
                                                                agg, Cc, G);
        scan_group_kernel<<<(B_*N_*H_)/256, 256, 0, stream>>>(agg, coef, lg2G);
        scan_fix_kernel<<<(B_*NG_*N_*H_)/256, 256, 0, stream>>>(states, coef,
                                                                agg, Cc, G);
        gemm_scan_kernel<3,256,false><<<(B_*256)/4, 256, 0, stream>>>(
            x, W_lin, b_lin, coef, states, D, film, out, nullptr);
    }
}